// Round 7
// baseline (232.556 us; speedup 1.0000x reference)
//
#include <hip/hip_runtime.h>

// ButterflyLinear: N=4096, DEPTH=12, TOKENS=8192, fp32.
// Structure (verified R0): all 12 stages act within aligned float4 groups ->
// network == block-diagonal 1024 x (4x4) linear map.
// R7: two kernels. Apply uses PLAIN cached loads (R6: NT forfeited ~50% L3
// hits) + explicit batch-of-8 prefetch (R6 showed VGPR=32 -> compiler kept
// the loop serial, 1 load in flight, latency-bound at 2.6 TB/s). All 8 token
// loads are issued before any use: ~32 waves/CU x 8 x 16B = 4KB outstanding
// per CU -> enough to cover ~400cyc mixed L3/HBM latency.

#define NFEAT   4096
#define DEPTH   12
#define NPAIR   (NFEAT / 2)
#define NGROUPS (NFEAT / 4)      // 1024
#define TOKENS  8192
#define GBLK    256
#define TOK_PER_BLK 8

typedef float fx4 __attribute__((ext_vector_type(4)));

__device__ __forceinline__ float4 stage0_apply(float4 v, float4 a, float4 b) {
    // pairs (v0,v1) w/ a, (v2,v3) w/ b
    return make_float4(v.x * a.x + v.y * a.z,
                       v.x * a.y + v.y * a.w,
                       v.z * b.x + v.w * b.z,
                       v.z * b.y + v.w * b.w);
}
__device__ __forceinline__ float4 stageS_apply(float4 v, float4 a, float4 b) {
    // pairs (v0,v2) w/ a, (v1,v3) w/ b
    return make_float4(v.x * a.x + v.z * a.z,
                       v.y * b.x + v.w * b.z,
                       v.x * a.y + v.z * a.w,
                       v.y * b.y + v.w * b.w);
}

// ---- kernel 1: compose the 4x4 map per group (4 column vectors) ----
__global__ __launch_bounds__(64)
void compose_kernel(const float* __restrict__ factors, float* __restrict__ M)
{
    const int k = blockIdx.x * 64 + threadIdx.x;   // group 0..1023

    float4 c0 = make_float4(1.f, 0.f, 0.f, 0.f);
    float4 c1 = make_float4(0.f, 1.f, 0.f, 0.f);
    float4 c2 = make_float4(0.f, 0.f, 1.f, 0.f);
    float4 c3 = make_float4(0.f, 0.f, 0.f, 1.f);

    {   // stage 0: factors 2k, 2k+1
        const float4 a = *(const float4*)(factors + (size_t)(2 * k    ) * 4);
        const float4 b = *(const float4*)(factors + (size_t)(2 * k + 1) * 4);
        c0 = stage0_apply(c0, a, b);
        c1 = stage0_apply(c1, a, b);
        c2 = stage0_apply(c2, a, b);
        c3 = stage0_apply(c3, a, b);
    }
#pragma unroll
    for (int s = 1; s < DEPTH; ++s) {
        const int lowmask = (1 << (s - 1)) - 1;
        const int p0 = ((k >> (s - 1)) << s) | (k & lowmask);
        const int p1 = p0 + (1 << (s - 1));
        const float4 a = *(const float4*)(factors + (size_t)(s * NPAIR + p0) * 4);
        const float4 b = *(const float4*)(factors + (size_t)(s * NPAIR + p1) * 4);
        c0 = stageS_apply(c0, a, b);
        c1 = stageS_apply(c1, a, b);
        c2 = stageS_apply(c2, a, b);
        c3 = stageS_apply(c3, a, b);
    }

    float4* m = (float4*)(M + (size_t)k * 16);
    m[0] = c0; m[1] = c1; m[2] = c2; m[3] = c3;
}

// ---- kernel 2: out[b] = M_k * x[b] + bias; batch-8 prefetch, cached ----
__global__ __launch_bounds__(GBLK)
void apply_kernel(const float* __restrict__ x,
                  const float* __restrict__ M,
                  const float* __restrict__ bias,
                  float* __restrict__ out)
{
    const int k    = blockIdx.x * GBLK + threadIdx.x;   // group 0..1023
    const int tok0 = blockIdx.y * TOK_PER_BLK;

    const float* xp = x   + (size_t)tok0 * NFEAT + 4 * k;
    float*       op = out + (size_t)tok0 * NFEAT + 4 * k;

    // issue ALL token loads first -> 8 independent reads in flight per lane
    fx4 v[TOK_PER_BLK];
#pragma unroll
    for (int t = 0; t < TOK_PER_BLK; ++t)
        v[t] = *(const fx4*)(xp + (size_t)t * NFEAT);

    const fx4* mp = (const fx4*)(M + (size_t)k * 16);
    const fx4 c0 = mp[0], c1 = mp[1], c2 = mp[2], c3 = mp[3];
    const fx4 bv = *(const fx4*)(bias + 4 * k);

#pragma unroll
    for (int t = 0; t < TOK_PER_BLK; ++t) {
        const fx4 u = v[t];                             // static index
        fx4 r;
        r.x = bv.x + u.x * c0.x + u.y * c1.x + u.z * c2.x + u.w * c3.x;
        r.y = bv.y + u.x * c0.y + u.y * c1.y + u.z * c2.y + u.w * c3.y;
        r.z = bv.z + u.x * c0.z + u.y * c1.z + u.z * c2.z + u.w * c3.z;
        r.w = bv.w + u.x * c0.w + u.y * c1.w + u.z * c2.w + u.w * c3.w;
        *(fx4*)(op + (size_t)t * NFEAT) = r;
    }
}

extern "C" void kernel_launch(void* const* d_in, const int* in_sizes, int n_in,
                              void* d_out, int out_size, void* d_ws, size_t ws_size,
                              hipStream_t stream) {
    const float* x       = (const float*)d_in[0];
    const float* factors = (const float*)d_in[1];
    const float* bias    = (const float*)d_in[2];
    float* out           = (float*)d_out;
    float* M             = (float*)d_ws;    // 1024 * 16 floats = 64 KB

    compose_kernel<<<dim3(NGROUPS / 64), dim3(64), 0, stream>>>(factors, M);

    dim3 grid(NGROUPS / GBLK, TOKENS / TOK_PER_BLK);   // (4, 1024) = 4096 blocks
    apply_kernel<<<grid, dim3(GBLK), 0, stream>>>(x, M, bias, out);
}